// Round 20
// baseline (349.801 us; speedup 1.0000x reference)
//
#include <hip/hip_runtime.h>

typedef _Float16 f16x8 __attribute__((ext_vector_type(8)));
typedef _Float16 f16x4 __attribute__((ext_vector_type(4)));
typedef __fp16   fp16x2 __attribute__((ext_vector_type(2)));
typedef float    f32x4 __attribute__((ext_vector_type(4)));
typedef unsigned int u32x2 __attribute__((ext_vector_type(2)));

__device__ __forceinline__ f32x4 mfma32(f16x8 a, f16x8 b, f32x4 c) {
  return __builtin_amdgcn_mfma_f32_16x16x32_f16(a, b, c, 0, 0, 0);
}
__device__ __forceinline__ f32x4 mfma16(f16x4 a, f16x4 b, f32x4 c) {
#if __has_builtin(__builtin_amdgcn_mfma_f32_16x16x16f16)
  return __builtin_amdgcn_mfma_f32_16x16x16f16(a, b, c, 0, 0, 0);
#else
  f32x4 d;
  asm volatile("v_mfma_f32_16x16x16_f16 %0, %1, %2, %3"
               : "=v"(d) : "v"(a), "v"(b), "v"(c));
  return d;
#endif
}

__device__ __forceinline__ unsigned pk2(float a, float b) {
  union { fp16x2 h; unsigned u; } cv;
  cv.h = __builtin_amdgcn_cvt_pkrtz(a, b);
  return cv.u;
}

// hardware transpose read: per-lane vaddr (32-bit LDS byte offset) = base + 8*lane
#define TR_READ(dst, addr, OFF) \
  asm volatile("ds_read_b64_tr_b16 %0, %1 offset:" OFF \
               : "=v"(dst) : "v"(addr) : "memory")

// ---- pre-convert weights to fp16 in workspace (L2-resident reuse) ----
__global__ void cvt_weights(const float* __restrict__ qw, const float* __restrict__ cw,
                            _Float16* __restrict__ wq, _Float16* __restrict__ wc) {
  const int i = blockIdx.x * 256 + threadIdx.x;
  if (i < 384 * 128) wq[i] = (_Float16)qw[i];
  if (i < 128 * 128) wc[i] = (_Float16)cw[i];
}

// PERSISTENT 8-window pipeline: grid 512 = 2 blocks/CU, ALL resident (no
// sequential launch rounds). Block owns 8 ww-consecutive windows (hh/dd/bb
// constant). Per iter: loads(w+1) -> QKV(w) -> stage_write(w+1) -> attn(w) ->
// B -> conv(w) -> B. va lives only across QKV (R17/18 spill fix); last iter
// PEELED so the rolled loop has no conditional defs (R6/R7 lesson). P stays
// in LDS (R19: reg-P shuffle chains were slower than overlapping LDS ops).
// v-first QKV ordering lets k overwrite v's LDS after av regs are read ->
// wsm 4KB/wave. o written directly to obuf per tj-pair (no opk regs),
// softmax normalization deferred to the o-scale, LOG2E folded into q.
// LDS (80KB, 2 blocks/CU): xbuf[2][16KB] x double-buffer; obuf[16KB];
//   wsm[wv] (4KB): v [0,2KB) [c][s] (overwritten by k), q [2KB,4KB) tr-layout,
//   P chunk [32t][64s] overlays [0,4KB) after tr-reads.
__global__ void __launch_bounds__(512, 4)
win_attn(const float* __restrict__ xg, const _Float16* __restrict__ wq,
         const float* __restrict__ qbias, const _Float16* __restrict__ wc,
         const float* __restrict__ cb, float* __restrict__ outg)
{
  __shared__ char xbuf[2][16384];
  __shared__ char obuf[16384];
  __shared__ char wsm[8][4096];

  const int tid  = threadIdx.x;
  const int lane = tid & 63;
  const int wv   = tid >> 6;          // 0..7 = head
  const int l15  = lane & 15;
  const int g    = lane >> 4;

  // XCD-bijective swizzle over blocks (512 % 8 == 0); block -> 8 windows
  const int raw = blockIdx.x;
  const int bsw = ((raw & 7) << 6) | (raw >> 3);
  const int wid0 = bsw * 8;
  const int wwbase = wid0 & 15;                 // 0 or 8
  const int hh = (wid0 >> 4) & 15, dd = (wid0 >> 8) & 7, bb = wid0 >> 11;

  const f32x4 fz = {0.f, 0.f, 0.f, 0.f};
  const int swzA = l15 << 4;
  const int vswz = (l15 & 7) << 4;

  char* sb = wsm[wv];
  const unsigned sb32 = (unsigned)(unsigned long long)sb;
  const unsigned trb  = sb32 + 8u * (unsigned)lane;

  const unsigned long long pmh = (hh == 15) ? 0xFF00FF00FF00FF00ull : 0ull;

  // staging geometry (constant across the block's 8 windows except ww)
  const int m4 = lane & 3, q4 = lane >> 2;
  const int i0 = q4 >> 2, i1 = q4 & 3;
  const int z = dd * 4 + i0, y = hh * 4 + i1;
  const bool yv = (y < 62);

  auto stage_loads = [&](int wwl, float (&va)[4][4]) {
    const bool full = (wwl < 15);
#pragma unroll
    for (int it = 0; it < 4; ++it) {
      const int c = wv * 16 + it * 4 + m4;
      const float* src = xg + (((size_t)(bb * 128 + c) * 32 + (size_t)z) * 3844
                               + (size_t)(y * 62 + wwl * 4));
      float a0 = 0.f, a1 = 0.f, a2 = 0.f, a3 = 0.f;
      if (yv) {
        const float2 lo = *reinterpret_cast<const float2*>(src);
        a0 = lo.x; a1 = lo.y;
        if (full) {
          const float2 hi = *reinterpret_cast<const float2*>(src + 2);
          a2 = hi.x; a3 = hi.y;
        }
      }
      va[it][0] = a0; va[it][1] = a1; va[it][2] = a2; va[it][3] = a3;
    }
  };
  auto stage_write = [&](char* xb, float (&va)[4][4]) {
#pragma unroll
    for (int it = 0; it < 4; ++it) {
      float v0 = va[it][0], v1 = va[it][1], v2 = va[it][2], v3 = va[it][3];
      float t0 = __shfl_xor((m4 & 1) ? v0 : v1, 1);
      float t1 = __shfl_xor((m4 & 1) ? v2 : v3, 1);
      if (m4 & 1) { v0 = t0; v2 = t1; } else { v1 = t0; v3 = t1; }
      float t2 = __shfl_xor((m4 & 2) ? v0 : v2, 2);
      float t3 = __shfl_xor((m4 & 2) ? v1 : v3, 2);
      if (m4 & 2) { v0 = t2; v1 = t3; } else { v2 = t2; v3 = t3; }
      f16x4 pk; pk[0] = (_Float16)v0; pk[1] = (_Float16)v1;
                pk[2] = (_Float16)v2; pk[3] = (_Float16)v3;
      const int c0 = wv * 16 + it * 4;         // lane holds xs[t=lane][c0..c0+3]
      *reinterpret_cast<f16x4*>(xb + ((lane * 256 + 2 * c0) ^ ((lane & 15) << 4))) = pk;
    }
  };

  // ---- QKV GEMM, v FIRST (av -> regs, k overwrites v region), then q, k ----
  auto qkv = [&](const char* xb, f16x8& av0, f16x8& av1) {
    // v
    {
      f32x4 acc[4] = {fz, fz, fz, fz};
      const int col = 256 + wv * 16 + l15;
      __builtin_amdgcn_s_setprio(1);
#pragma unroll
      for (int kk = 0; kk < 4; ++kk) {
        const f16x8 bfr = *reinterpret_cast<const f16x8*>(wq + col * 128 + kk * 32 + g * 8);
#pragma unroll
        for (int ri = 0; ri < 4; ++ri) {
          const f16x8 a = *reinterpret_cast<const f16x8*>(
              xb + (ri * 16 + l15) * 256 + ((kk * 64 + g * 16) ^ swzA));
          acc[ri] = mfma32(a, bfr, acc[ri]);
        }
      }
      __builtin_amdgcn_s_setprio(0);
      const float bias = qbias[col];
#pragma unroll
      for (int ri = 0; ri < 4; ++ri) {
        const int s0 = ri * 16 + g * 4;
        *reinterpret_cast<unsigned*>(sb + l15 * 128 + ((2 * s0) ^ vswz))
            = pk2(acc[ri][0] + bias, acc[ri][1] + bias);
        *reinterpret_cast<unsigned*>(sb + l15 * 128 + ((2 * (s0 + 2)) ^ vswz))
            = pk2(acc[ri][2] + bias, acc[ri][3] + bias);
      }
    }
    asm volatile("s_waitcnt lgkmcnt(0)" ::: "memory");
    av0 = *reinterpret_cast<const f16x8*>(sb + l15 * 128 + ((g * 16) ^ vswz));
    av1 = *reinterpret_cast<const f16x8*>(sb + l15 * 128 + ((64 + g * 16) ^ vswz));
    // q then k (k overwrites the dead v region)
#pragma unroll
    for (int co = 0; co < 2; ++co) {
      f32x4 acc[4] = {fz, fz, fz, fz};
      const int col = co * 128 + wv * 16 + l15;
      __builtin_amdgcn_s_setprio(1);
#pragma unroll
      for (int kk = 0; kk < 4; ++kk) {
        const f16x8 bfr = *reinterpret_cast<const f16x8*>(wq + col * 128 + kk * 32 + g * 8);
#pragma unroll
        for (int ri = 0; ri < 4; ++ri) {
          const f16x8 a = *reinterpret_cast<const f16x8*>(
              xb + (ri * 16 + l15) * 256 + ((kk * 64 + g * 16) ^ swzA));
          acc[ri] = mfma32(a, bfr, acc[ri]);
        }
      }
      __builtin_amdgcn_s_setprio(0);
      const float bias = qbias[col];
      // q scale folds softmax 0.25 AND log2(e) (exp2 used directly in softmax)
      const float sc = (co == 0) ? 0.25f * 1.4426950408889634f : 1.0f;
      const int base = (co == 0) ? 2048 : 0;
#pragma unroll
      for (int ri = 0; ri < 4; ++ri) {
        const int off = ri * 512 + l15 * 32 + g * 8;  // bytes
        u32x2 w;
        w[0] = pk2((acc[ri][0] + bias) * sc, (acc[ri][1] + bias) * sc);
        w[1] = pk2((acc[ri][2] + bias) * sc, (acc[ri][3] + bias) * sc);
        *reinterpret_cast<u32x2*>(sb + base + off) = w;
      }
    }
  };

  // ---- attention for one window; o -> obuf directly (deferred normalization) ----
  auto attn = [&](unsigned long long pm, f16x8 av0, f16x8 av1) {
    asm volatile("s_waitcnt lgkmcnt(0)" ::: "memory");
    f16x4 ka[4], qa[4];
    TR_READ(ka[0], trb, "0");
    TR_READ(ka[1], trb, "512");
    TR_READ(ka[2], trb, "1024");
    TR_READ(ka[3], trb, "1536");
    TR_READ(qa[0], trb, "2048");
    TR_READ(qa[1], trb, "2560");
    TR_READ(qa[2], trb, "3072");
    TR_READ(qa[3], trb, "3584");
    asm volatile("s_waitcnt lgkmcnt(0)" ::: "memory");
    __builtin_amdgcn_sched_barrier(0);           // rule #18: fence tr_read -> mfma

#pragma unroll
    for (int tjp = 0; tjp < 2; ++tjp) {
      const int tj0 = 2 * tjp, tj1 = 2 * tjp + 1;
      f32x4 st2[4][2];
#pragma unroll
      for (int si = 0; si < 4; ++si) {
        st2[si][0] = mfma16(ka[si], qa[tj0], fz);
        st2[si][1] = mfma16(ka[si], qa[tj1], fz);
      }

      if (pm) {
#pragma unroll
        for (int tjc = 0; tjc < 2; ++tjc) {
          const int t = (2 * tjp + tjc) * 16 + l15;
          const unsigned ft = (unsigned)(pm >> t) & 1u;
#pragma unroll
          for (int si = 0; si < 4; ++si)
#pragma unroll
            for (int r = 0; r < 4; ++r) {
              const int s = si * 16 + g * 4 + r;
              const unsigned fs = (unsigned)(pm >> s) & 1u;
              if (fs != ft) st2[si][tjc][r] -= 1000.f;
            }
        }
      }

      // softmax over s: exp2(x - mx), UNNORMALIZED; 1/sum kept per tjc
      float invs[2];
#pragma unroll
      for (int tjc = 0; tjc < 2; ++tjc) {
        float mx = st2[0][tjc][0];
#pragma unroll
        for (int si = 0; si < 4; ++si)
#pragma unroll
          for (int r = 0; r < 4; ++r) mx = fmaxf(mx, st2[si][tjc][r]);
        mx = fmaxf(mx, __shfl_xor(mx, 16));
        mx = fmaxf(mx, __shfl_xor(mx, 32));
        float sum = 0.f;
#pragma unroll
        for (int si = 0; si < 4; ++si)
#pragma unroll
          for (int r = 0; r < 4; ++r) {
            const float e = __builtin_amdgcn_exp2f(st2[si][tjc][r] - mx);
            st2[si][tjc][r] = e; sum += e;
          }
        sum += __shfl_xor(sum, 16);
        sum += __shfl_xor(sum, 32);
        invs[tjc] = __builtin_amdgcn_rcpf(sum);
      }

      // write P chunk [32 t_local][64 s] (overlays k/q region, both consumed)
#pragma unroll
      for (int tjc = 0; tjc < 2; ++tjc) {
        const int tl = tjc * 16 + l15;
#pragma unroll
        for (int si = 0; si < 4; ++si) {
          u32x2 w;
          w[0] = pk2(st2[si][tjc][0], st2[si][tjc][1]);
          w[1] = pk2(st2[si][tjc][2], st2[si][tjc][3]);
          *reinterpret_cast<u32x2*>(sb + tl * 128 + ((si * 32 + g * 8) ^ vswz)) = w;
        }
      }
      asm volatile("s_waitcnt lgkmcnt(0)" ::: "memory");

      // PV
      f32x4 oa0 = fz, oa1 = fz;
      {
        const f16x8 pa00 = *reinterpret_cast<const f16x8*>(
            sb + l15 * 128 + ((g * 16) ^ vswz));
        const f16x8 pa10 = *reinterpret_cast<const f16x8*>(
            sb + (16 + l15) * 128 + ((g * 16) ^ vswz));
        __builtin_amdgcn_s_setprio(1);
        oa0 = mfma32(av0, pa00, oa0);
        oa1 = mfma32(av0, pa10, oa1);
        const f16x8 pa01 = *reinterpret_cast<const f16x8*>(
            sb + l15 * 128 + ((64 + g * 16) ^ vswz));
        const f16x8 pa11 = *reinterpret_cast<const f16x8*>(
            sb + (16 + l15) * 128 + ((64 + g * 16) ^ vswz));
        oa0 = mfma32(av1, pa01, oa0);
        oa1 = mfma32(av1, pa11, oa1);
        __builtin_amdgcn_s_setprio(0);
      }

      // deferred normalization + o -> obuf (lane holds o[c = wv*16+g*4+r][t])
      {
        const int t0 = tj0 * 16 + l15;
        u32x2 w0;
        w0[0] = pk2(oa0[0] * invs[0], oa0[1] * invs[0]);
        w0[1] = pk2(oa0[2] * invs[0], oa0[3] * invs[0]);
        *reinterpret_cast<u32x2*>(obuf + t0 * 256 + ((wv * 32 + g * 8) ^ ((t0 & 15) << 4))) = w0;
        const int t1 = tj1 * 16 + l15;
        u32x2 w1;
        w1[0] = pk2(oa1[0] * invs[1], oa1[1] * invs[1]);
        w1[1] = pk2(oa1[2] * invs[1], oa1[3] * invs[1]);
        *reinterpret_cast<u32x2*>(obuf + t1 * 256 + ((wv * 32 + g * 8) ^ ((t1 & 15) << 4))) = w1;
      }
    }
  };

  auto conv_store = [&](int wwl) {
    f32x4 cacc[4] = {fz, fz, fz, fz};
    const int cout = wv * 16 + l15;
    __builtin_amdgcn_s_setprio(1);
#pragma unroll
    for (int kk = 0; kk < 4; ++kk) {
      const f16x8 bfr = *reinterpret_cast<const f16x8*>(wc + cout * 128 + kk * 32 + g * 8);
#pragma unroll
      for (int ri = 0; ri < 4; ++ri) {
        const f16x8 a = *reinterpret_cast<const f16x8*>(
            obuf + (ri * 16 + l15) * 256 + ((kk * 64 + g * 16) ^ swzA));
        cacc[ri] = mfma32(a, bfr, cacc[ri]);
      }
    }
    __builtin_amdgcn_s_setprio(0);
    const int yy = hh * 4 + g;
    if (yy < 62) {
      const float bias = cb[cout];
#pragma unroll
      for (int ri = 0; ri < 4; ++ri) {
        const int zz = dd * 4 + ri;
        float* dst = outg + (((size_t)(bb * 128 + cout) * 32 + (size_t)zz) * 3844
                             + (size_t)(yy * 62 + wwl * 4));
        float2 lo; lo.x = cacc[ri][0] + bias; lo.y = cacc[ri][1] + bias;
        *reinterpret_cast<float2*>(dst) = lo;
        if (wwl < 15) {
          float2 hi; hi.x = cacc[ri][2] + bias; hi.y = cacc[ri][3] + bias;
          *reinterpret_cast<float2*>(dst + 2) = hi;
        }
      }
    }
  };

  // ================= persistent 8-window pipeline =================
  char* pA = xbuf[0];
  char* pB = xbuf[1];
  f16x8 av0, av1;

  {
    float va[4][4];
    stage_loads(wwbase + 0, va);
    stage_write(pA, va);
  }
  __syncthreads();                         // buf A = window 0

#pragma unroll 1
  for (int w = 0; w < 7; ++w) {
    const int wwl = wwbase + w;
    {
      float va[4][4];
      stage_loads(wwl + 1, va);            // issue next-window loads
      qkv(pA, av0, av1);                   // long compute hides the latency
      stage_write(pB, va);                 // va dies here (short lifetime)
    }
    attn(pmh | ((wwl == 15) ? 0xCCCCCCCCCCCCCCCCull : 0ull), av0, av1);
    __syncthreads();                       // obuf + buf B ready; buf A free
    conv_store(wwl);
    __syncthreads();                       // obuf consumed; safe to refill
    char* tmp = pA; pA = pB; pB = tmp;
  }
  // peeled last window (no prefetch)
  {
    const int wwl = wwbase + 7;
    qkv(pA, av0, av1);
    attn(pmh | ((wwl == 15) ? 0xCCCCCCCCCCCCCCCCull : 0ull), av0, av1);
    __syncthreads();
    conv_store(wwl);
  }
}

extern "C" void kernel_launch(void* const* d_in, const int* in_sizes, int n_in,
                              void* d_out, int out_size, void* d_ws, size_t ws_size,
                              hipStream_t stream) {
  const float* x  = (const float*)d_in[0];
  const float* qw = (const float*)d_in[1];
  const float* qb = (const float*)d_in[2];
  const float* cw = (const float*)d_in[3];
  const float* cb = (const float*)d_in[4];
  float* out = (float*)d_out;

  if (ws_size < (size_t)(384 * 128 + 128 * 128) * sizeof(_Float16)) return;
  _Float16* wq = (_Float16*)d_ws;
  _Float16* wc = wq + 384 * 128;

  cvt_weights<<<192, 256, 0, stream>>>(qw, cw, wq, wc);
  win_attn<<<512, 512, 0, stream>>>(x, wq, qb, wc, cb, out);
}